// Round 5
// baseline (2301.932 us; speedup 1.0000x reference)
//
#include <hip/hip_runtime.h>
#include <hip/hip_bf16.h>

#define NROW 50000
#define NCOL 50000
#define DDIM 128

typedef __bf16 bf16_t;
typedef __bf16 bf16x8 __attribute__((ext_vector_type(8)));
typedef float  f32x4  __attribute__((ext_vector_type(4)));

__device__ __forceinline__ float lrelu(float v) { return v >= 0.f ? v : 0.01f * v; }

// adaptive scalar load: f ? f32 : bf16
__device__ __forceinline__ float ldf(const void* p, size_t i, bool f) {
    return f ? ((const float*)p)[i] : (float)((const bf16_t*)p)[i];
}

// ---------------- dtype detector (worked in round 4 — unchanged) ----------
// For bf16 data, low 16 bits of each 32b word are a bf16 with a plausible
// exponent (90..141 for this problem's value ranges). For f32 data they are
// uniform mantissa bits (~20% in range). Majority vote over 256 samples.
struct TensorTab { const void* p[18]; int n[18]; };

__global__ __launch_bounds__(256) void detect_dtypes(TensorTab T, int* flags)
{
    __shared__ int vb, vf;
    const int tid = threadIdx.x;
    for (int t = 0; t < 18; ++t) {
        if (tid == 0) { vb = 0; vf = 0; }
        __syncthreads();
        const int n = T.n[t];
        const bool isFloatArr = (t != 2 && t != 3 && t != 5 && t != 6) && n >= 2;
        if (isFloatArr) {
            int nw = n / 2;  // words in-bounds under EITHER dtype hypothesis
            int wi = (int)(((long long)tid * nw) >> 8);
            unsigned w = ((const unsigned*)T.p[t])[wi];
            unsigned low = w & 0xffffu;
            if (low) {
                int e = (int)((low >> 7) & 0xffu);
                if (e >= 90 && e <= 141) atomicAdd(&vb, 1);
                else                     atomicAdd(&vf, 1);
            }
        }
        __syncthreads();
        if (tid == 0) flags[t] = (isFloatArr && vf > vb) ? 1 : 0; // 1 = f32
        __syncthreads();
    }
}

// ---------- edge scatter: agg[dst] += feat[src] * w  (f32 agg, HW atomic) --
// 32 threads per edge, 4 dims per thread. fi==-1 forces f32.
__global__ __launch_bounds__(256) void scatter_any(
    const void* __restrict__ feat, const int* __restrict__ src,
    const int* __restrict__ dst, const void* __restrict__ w,
    float* __restrict__ agg, int nE,
    const int* __restrict__ flags, int fiFeat, int fiW)
{
    const bool fF = (fiFeat == -1) ? true : (flags[fiFeat] != 0);
    const bool fW = (fiW   == -1) ? true : (flags[fiW]   != 0);
    int g = blockIdx.x * 256 + threadIdx.x;
    int e = g >> 5;
    if (e >= nE) return;
    int c = (g & 31) << 2;
    int s = src[e], d = dst[e];
    float wf = ldf(w, e, fW);
    size_t base = (size_t)s * DDIM + c;
    float* ap = agg + (size_t)d * DDIM + c;
    unsafeAtomicAdd(ap + 0, ldf(feat, base + 0, fF) * wf);
    unsafeAtomicAdd(ap + 1, ldf(feat, base + 1, fF) * wf);
    unsafeAtomicAdd(ap + 2, ldf(feat, base + 2, fF) * wf);
    unsafeAtomicAdd(ap + 3, ldf(feat, base + 3, fF) * wf);
}

// ---------- out(f32) += feat (adaptive) ----------
__global__ __launch_bounds__(256) void residual_add(
    float* __restrict__ out, const void* __restrict__ feat, int n4,
    const int* __restrict__ flags, int fiFeat)
{
    const bool fF = flags[fiFeat] != 0;
    int i = blockIdx.x * 256 + threadIdx.x;
    if (i >= n4) return;
    f32x4 o = ((const f32x4*)out)[i];
    f32x4 r;
#pragma unroll
    for (int j = 0; j < 4; ++j) r[j] = o[j] + ldf(feat, (size_t)i * 4 + j, fF);
    ((f32x4*)out)[i] = r;
}

// ---------- fused MLP: h = leaky(leaky(x@W1+b1)@W2+b2); out = h (+feat) ----
// x = (1+eps)*feat + agg.  64 rows per workgroup, 4 waves x 16 rows.
__device__ __forceinline__ void fill_wfrag(const void* __restrict__ W, bool f,
                                           __bf16* wf, int tid)
{
#pragma unroll
    for (int i = 0; i < 8; ++i) {
        int sIdx  = tid + i * 256;
        int l     = sIdx & 63;
        int combo = sIdx >> 6;
        int ct = combo >> 2, kk = combo & 3;
        int col  = ct * 16 + (l & 15);
        int krow = kk * 32 + (l >> 4) * 8;
        __bf16* dp = wf + (size_t)sIdx * 8;
#pragma unroll
        for (int j = 0; j < 8; ++j)
            dp[j] = (__bf16)ldf(W, (size_t)(krow + j) * DDIM + col, f);
    }
}

template <bool RESIDUAL>
__global__ __launch_bounds__(256) void mlp_kernel(
    const void* __restrict__ feat, const float* __restrict__ agg,
    const void* __restrict__ W1, const void* __restrict__ b1,
    const void* __restrict__ W2, const void* __restrict__ b2,
    const void* __restrict__ epsp, float* __restrict__ out, int N,
    const int* __restrict__ flags,
    int fiFeat, int fiW1, int fiB1, int fiW2, int fiB2, int fiEps)
{
    __shared__ alignas(16) __bf16 wf[32 * 64 * 8];  // 32 KB weight B-frags
    __shared__ alignas(16) __bf16 h1t[64 * 136];    // 17 KB h1 tile (+8 pad)

    const bool fF  = flags[fiFeat] != 0;
    const bool fW1 = flags[fiW1] != 0, fB1 = flags[fiB1] != 0;
    const bool fW2 = flags[fiW2] != 0, fB2 = flags[fiB2] != 0;
    const bool fE  = flags[fiEps] != 0;

    const int tid  = threadIdx.x;
    const int lane = tid & 63;
    const int wave = tid >> 6;
    const int quad = lane >> 4;
    const int r    = lane & 15;

    fill_wfrag(W1, fW1, wf, tid);

    const float eps1 = 1.f + ldf(epsp, 0, fE);
    const int rowBase = blockIdx.x * 64 + wave * 16;

    // A-fragments for layer 1: x[rowBase+r][k], k = kk*32 + quad*8 + j
    bf16x8 a[4];
    {
        int rowA = rowBase + r;
        if (rowA < N) {
            size_t fb = (size_t)rowA * DDIM + quad * 8;
#pragma unroll
            for (int kk = 0; kk < 4; ++kk) {
                bf16x8 av;
#pragma unroll
                for (int j = 0; j < 8; ++j) {
                    float fv = ldf(feat, fb + kk * 32 + j, fF);
                    float gv = agg[fb + kk * 32 + j];
                    av[j] = (__bf16)(fv * eps1 + gv);
                }
                a[kk] = av;
            }
        } else {
#pragma unroll
            for (int kk = 0; kk < 4; ++kk)
#pragma unroll
                for (int j = 0; j < 8; ++j) a[kk][j] = (__bf16)0.f;
        }
    }

    __syncthreads();  // weights ready; all agg reads above are complete

    const bf16x8* wv = (const bf16x8*)wf;
#pragma unroll
    for (int ct = 0; ct < 8; ++ct) {
        f32x4 acc = {0.f, 0.f, 0.f, 0.f};
#pragma unroll
        for (int kk = 0; kk < 4; ++kk)
            acc = __builtin_amdgcn_mfma_f32_16x16x32_bf16(
                a[kk], wv[(ct * 4 + kk) * 64 + lane], acc, 0, 0, 0);
        float bias = ldf(b1, ct * 16 + r, fB1);
#pragma unroll
        for (int gg = 0; gg < 4; ++gg)   // D: m = quad*4+gg, n = ct*16+r
            h1t[(wave * 16 + quad * 4 + gg) * 136 + ct * 16 + r] =
                (__bf16)lrelu(acc[gg] + bias);
    }
    __syncthreads();  // h1 complete; wf free to reuse

    bf16x8 a2[4];
#pragma unroll
    for (int kk = 0; kk < 4; ++kk)
        a2[kk] = *(const bf16x8*)&h1t[(wave * 16 + r) * 136 + kk * 32 + quad * 8];

    fill_wfrag(W2, fW2, wf, tid);
    __syncthreads();  // W2 frags ready

#pragma unroll
    for (int ct = 0; ct < 8; ++ct) {
        f32x4 acc = {0.f, 0.f, 0.f, 0.f};
#pragma unroll
        for (int kk = 0; kk < 4; ++kk)
            acc = __builtin_amdgcn_mfma_f32_16x16x32_bf16(
                a2[kk], wv[(ct * 4 + kk) * 64 + lane], acc, 0, 0, 0);
        float bias = ldf(b2, ct * 16 + r, fB2);
#pragma unroll
        for (int gg = 0; gg < 4; ++gg) {
            int row = rowBase + quad * 4 + gg;
            if (row < N) {
                int col = ct * 16 + r;
                float v = lrelu(acc[gg] + bias);
                if (RESIDUAL) v += ldf(feat, (size_t)row * DDIM + col, fF);
                out[(size_t)row * DDIM + col] = v;
            }
        }
    }
}

extern "C" void kernel_launch(void* const* d_in, const int* in_sizes, int n_in,
                              void* d_out, int out_size, void* d_ws, size_t ws_size,
                              hipStream_t stream)
{
    const int* src_c2r = (const int*)d_in[2];
    const int* dst_c2r = (const int*)d_in[3];
    const int* src_r2c = (const int*)d_in[5];
    const int* dst_r2c = (const int*)d_in[6];

    const int nE = in_sizes[2];

    int* flags = (int*)d_ws;                       // 18 ints = 72 B of ws

    TensorTab T;
    for (int i = 0; i < 18; ++i) { T.p[i] = d_in[i]; T.n[i] = in_sizes[i]; }

    // OUTPUT IS F32 (reference's dtype). out_col half doubles as f32 agg.
    float* out_row = (float*)d_out;
    float* out_col = out_row + (size_t)NROW * DDIM;
    const size_t aggBytes = (size_t)NROW * DDIM * sizeof(float);  // 25.6 MB

    const int sblocks  = (nE * 32 + 255) / 256;
    const int mblocksR = (NROW + 63) / 64;
    const int mblocksC = (NCOL + 63) / 64;

    detect_dtypes<<<1, 256, 0, stream>>>(T, flags);

    // ---- stage 1: col -> row (agg_row accumulates f32 in out_col region) --
    hipMemsetAsync(out_col, 0, aggBytes, stream);
    scatter_any<<<sblocks, 256, 0, stream>>>(d_in[1], src_c2r, dst_c2r, d_in[4],
                                             out_col, nE, flags, 1, 4);
    // out_row <- h_row (f32, NO residual yet; doubles as scatter-2 source)
    mlp_kernel<false><<<mblocksR, 256, 0, stream>>>(
        d_in[0], out_col, d_in[8], d_in[9], d_in[10], d_in[11], d_in[16],
        out_row, NROW, flags, 0, 8, 9, 10, 11, 16);

    // ---- stage 2: row -> col ----
    hipMemsetAsync(out_col, 0, aggBytes, stream);
    scatter_any<<<sblocks, 256, 0, stream>>>(out_row, src_r2c, dst_r2c, d_in[7],
                                             out_col, nE, flags, -1, 7);
    residual_add<<<(NROW * DDIM / 4 + 255) / 256, 256, 0, stream>>>(
        out_row, d_in[0], NROW * DDIM / 4, flags, 0);
    // mlp2 reads agg from out_col and overwrites out_col in place (safe:
    // per-block agg reads all precede the barrier before any out write;
    // blocks own disjoint 64-row ranges).
    mlp_kernel<true><<<mblocksC, 256, 0, stream>>>(
        d_in[1], out_col, d_in[12], d_in[13], d_in[14], d_in[15], d_in[17],
        out_col, NCOL, flags, 1, 12, 13, 14, 15, 17);
}

// Round 6
// 508.362 us; speedup vs baseline: 4.5281x; 4.5281x over previous
//
#include <hip/hip_runtime.h>
#include <hip/hip_bf16.h>

#define NROW 50000
#define NCOL 50000
#define DDIM 128
#define CAP  32   // slots per destination row

typedef __bf16 bf16_t;
typedef __bf16 bf16x2 __attribute__((ext_vector_type(2)));
typedef __bf16 bf16x8 __attribute__((ext_vector_type(8)));
typedef float  f32x4  __attribute__((ext_vector_type(4)));

__device__ __forceinline__ float lrelu(float v) { return v >= 0.f ? v : 0.01f * v; }

// adaptive scalar load: f ? f32 : bf16
__device__ __forceinline__ float ldf(const void* p, size_t i, bool f) {
    return f ? ((const float*)p)[i] : (float)((const bf16_t*)p)[i];
}

// ---------------- dtype detector (proven in rounds 4/5 — unchanged) --------
struct TensorTab { const void* p[18]; int n[18]; };

__global__ __launch_bounds__(256) void detect_dtypes(TensorTab T, int* flags)
{
    __shared__ int vb, vf;
    const int tid = threadIdx.x;
    for (int t = 0; t < 18; ++t) {
        if (tid == 0) { vb = 0; vf = 0; }
        __syncthreads();
        const int n = T.n[t];
        const bool isFloatArr = (t != 2 && t != 3 && t != 5 && t != 6) && n >= 2;
        if (isFloatArr) {
            int nw = n / 2;
            int wi = (int)(((long long)tid * nw) >> 8);
            unsigned w = ((const unsigned*)T.p[t])[wi];
            unsigned low = w & 0xffffu;
            if (low) {
                int e = (int)((low >> 7) & 0xffu);
                if (e >= 90 && e <= 141) atomicAdd(&vb, 1);
                else                     atomicAdd(&vf, 1);
            }
        }
        __syncthreads();
        if (tid == 0) flags[t] = (isFloatArr && vf > vb) ? 1 : 0; // 1 = f32
        __syncthreads();
    }
}

// ---------------- weight prep: rearrange 4 DxD matrices into MFMA B-frag
// order (slot sIdx -> 8 contiguous bf16). One-time, tiny.
struct WPtrs { const void* W[4]; int fi[4]; };

__global__ __launch_bounds__(256) void prep_weights(WPtrs P, const int* flags,
                                                    __bf16* outp)
{
    int slot = blockIdx.x * 256 + threadIdx.x;     // 4 * 2048
    if (slot >= 4 * 2048) return;
    int m = slot >> 11, sIdx = slot & 2047;
    bool f = flags[P.fi[m]] != 0;
    int l = sIdx & 63, combo = sIdx >> 6;
    int ct = combo >> 2, kk = combo & 3;
    int col  = ct * 16 + (l & 15);
    int krow = kk * 32 + (l >> 4) * 8;
    bf16x8 v;
#pragma unroll
    for (int j = 0; j < 8; ++j)
        v[j] = (__bf16)ldf(P.W[m], (size_t)(krow + j) * DDIM + col, f);
    ((bf16x8*)outp)[slot] = v;
}

// ---------------- bucket fill: one thread per edge --------------------------
__global__ __launch_bounds__(256) void fill_slots(
    const int* __restrict__ dst, int nE, int* __restrict__ counts,
    int* __restrict__ slots,
    const void* __restrict__ feat, const int* __restrict__ srcArr,
    const void* __restrict__ wArr, float* __restrict__ agg,
    const int* __restrict__ flags, int fiFeat, int fiW)
{
    int e = blockIdx.x * 256 + threadIdx.x;
    if (e >= nE) return;
    int d = dst[e];
    int pos = atomicAdd(&counts[d], 1);
    if (pos < CAP) {
        slots[(size_t)d * CAP + pos] = e;
    } else {  // rare overflow: exact fallback, direct atomic accumulation
        const bool fF = (fiFeat == -1) ? true : (flags[fiFeat] != 0);
        const bool fW = (fiW   == -1) ? true : (flags[fiW]   != 0);
        int s = srcArr[e];
        float wf = ldf(wArr, e, fW);
        for (int c = 0; c < DDIM; ++c)
            unsafeAtomicAdd(&agg[(size_t)d * DDIM + c],
                            ldf(feat, (size_t)s * DDIM + c, fF) * wf);
    }
}

// ---------------- segment sum: one wave per destination row ----------------
__global__ __launch_bounds__(256) void segsum(
    const void* __restrict__ feat, const int* __restrict__ srcArr,
    const void* __restrict__ wArr, const int* __restrict__ counts,
    const int* __restrict__ slots, float* __restrict__ agg, int nRows,
    const int* __restrict__ flags, int fiFeat, int fiW)
{
    const bool fF = (fiFeat == -1) ? true : (flags[fiFeat] != 0);
    const bool fW = (fiW   == -1) ? true : (flags[fiW]   != 0);
    int row = blockIdx.x * 4 + (threadIdx.x >> 6);
    if (row >= nRows) return;
    int lane = threadIdx.x & 63;

    float2* ap = (float2*)(agg + (size_t)row * DDIM) + lane;
    float2 s = *ap;                       // holds overflow contributions
    int cnt = counts[row]; if (cnt > CAP) cnt = CAP;
    const int* sl = slots + (size_t)row * CAP;

    for (int i = 0; i < cnt; ++i) {
        int e  = sl[i];
        int sr = srcArr[e];
        float wf = ldf(wArr, e, fW);
        float v0, v1;
        if (fF) {
            float2 v = ((const float2*)((const float*)feat + (size_t)sr * DDIM))[lane];
            v0 = v.x; v1 = v.y;
        } else {
            bf16x2 v = ((const bf16x2*)((const bf16_t*)feat + (size_t)sr * DDIM))[lane];
            v0 = (float)v[0]; v1 = (float)v[1];
        }
        s.x += v0 * wf; s.y += v1 * wf;
    }
    *ap = s;
}

// ---------------- legacy atomic scatter (ws-too-small fallback) -------------
__global__ __launch_bounds__(256) void scatter_any(
    const void* __restrict__ feat, const int* __restrict__ src,
    const int* __restrict__ dst, const void* __restrict__ w,
    float* __restrict__ agg, int nE,
    const int* __restrict__ flags, int fiFeat, int fiW)
{
    const bool fF = (fiFeat == -1) ? true : (flags[fiFeat] != 0);
    const bool fW = (fiW   == -1) ? true : (flags[fiW]   != 0);
    int g = blockIdx.x * 256 + threadIdx.x;
    int e = g >> 5;
    if (e >= nE) return;
    int c = (g & 31) << 2;
    int s = src[e], d = dst[e];
    float wf = ldf(w, e, fW);
    size_t base = (size_t)s * DDIM + c;
    float* ap = agg + (size_t)d * DDIM + c;
    unsafeAtomicAdd(ap + 0, ldf(feat, base + 0, fF) * wf);
    unsafeAtomicAdd(ap + 1, ldf(feat, base + 1, fF) * wf);
    unsafeAtomicAdd(ap + 2, ldf(feat, base + 2, fF) * wf);
    unsafeAtomicAdd(ap + 3, ldf(feat, base + 3, fF) * wf);
}

// ---------------- residual: out(f32) += feat (adaptive) --------------------
__global__ __launch_bounds__(256) void residual_add(
    float* __restrict__ out, const void* __restrict__ feat, int n4,
    const int* __restrict__ flags, int fiFeat)
{
    const bool fF = flags[fiFeat] != 0;
    int i = blockIdx.x * 256 + threadIdx.x;
    if (i >= n4) return;
    f32x4 o = ((const f32x4*)out)[i];
    f32x4 r;
#pragma unroll
    for (int j = 0; j < 4; ++j) r[j] = o[j] + ldf(feat, (size_t)i * 4 + j, fF);
    ((f32x4*)out)[i] = r;
}

// ---------------- fused MLP ------------------------------------------------
__device__ __forceinline__ void fill_wfrag(const void* __restrict__ W, bool f,
                                           __bf16* wf, int tid)
{
#pragma unroll
    for (int i = 0; i < 8; ++i) {
        int sIdx  = tid + i * 256;
        int l     = sIdx & 63;
        int combo = sIdx >> 6;
        int ct = combo >> 2, kk = combo & 3;
        int col  = ct * 16 + (l & 15);
        int krow = kk * 32 + (l >> 4) * 8;
        __bf16* dp = wf + (size_t)sIdx * 8;
#pragma unroll
        for (int j = 0; j < 8; ++j)
            dp[j] = (__bf16)ldf(W, (size_t)(krow + j) * DDIM + col, f);
    }
}

__device__ __forceinline__ void copy_wfrag(const __bf16* __restrict__ prep,
                                           __bf16* wf, int tid)
{
    const f32x4* sp = (const f32x4*)prep;
    f32x4* dp = (f32x4*)wf;
#pragma unroll
    for (int i = 0; i < 8; ++i) dp[tid + i * 256] = sp[tid + i * 256];
}

template <bool RESIDUAL, bool PREP>
__global__ __launch_bounds__(256) void mlp_kernel(
    const void* __restrict__ feat, const float* __restrict__ agg,
    const void* __restrict__ W1, const void* __restrict__ b1,
    const void* __restrict__ W2, const void* __restrict__ b2,
    const void* __restrict__ epsp, float* __restrict__ out, int N,
    const int* __restrict__ flags,
    int fiFeat, int fiW1, int fiB1, int fiW2, int fiB2, int fiEps,
    const __bf16* __restrict__ pW1, const __bf16* __restrict__ pW2)
{
    __shared__ alignas(16) __bf16 wf[32 * 64 * 8];  // 32 KB weight B-frags
    __shared__ alignas(16) __bf16 h1t[64 * 136];    // 17 KB h1 tile (+8 pad)

    const bool fF  = flags[fiFeat] != 0;
    const bool fB1 = flags[fiB1] != 0;
    const bool fB2 = flags[fiB2] != 0;
    const bool fE  = flags[fiEps] != 0;

    const int tid  = threadIdx.x;
    const int lane = tid & 63;
    const int wave = tid >> 6;
    const int quad = lane >> 4;
    const int r    = lane & 15;

    if (PREP) copy_wfrag(pW1, wf, tid);
    else      fill_wfrag(W1, flags[fiW1] != 0, wf, tid);

    const float eps1 = 1.f + ldf(epsp, 0, fE);
    const int rowBase = blockIdx.x * 64 + wave * 16;

    // A-fragments for layer 1: x[rowBase+r][k], k = kk*32 + quad*8 + j
    bf16x8 a[4];
    {
        int rowA = rowBase + r;
        if (rowA < N) {
            size_t fb = (size_t)rowA * DDIM + quad * 8;
            const f32x4* gp = (const f32x4*)(agg + fb);
            if (fF) {
                const f32x4* fp = (const f32x4*)((const float*)feat + fb);
#pragma unroll
                for (int kk = 0; kk < 4; ++kk) {
                    f32x4 f0 = fp[kk * 8], f1 = fp[kk * 8 + 1];
                    f32x4 g0 = gp[kk * 8], g1 = gp[kk * 8 + 1];
                    bf16x8 av;
#pragma unroll
                    for (int j = 0; j < 4; ++j) {
                        av[j]     = (__bf16)(f0[j] * eps1 + g0[j]);
                        av[j + 4] = (__bf16)(f1[j] * eps1 + g1[j]);
                    }
                    a[kk] = av;
                }
            } else {
                const bf16x8* fp = (const bf16x8*)((const bf16_t*)feat + fb);
#pragma unroll
                for (int kk = 0; kk < 4; ++kk) {
                    bf16x8 fv = fp[kk * 4];
                    f32x4 g0 = gp[kk * 8], g1 = gp[kk * 8 + 1];
                    bf16x8 av;
#pragma unroll
                    for (int j = 0; j < 4; ++j) {
                        av[j]     = (__bf16)((float)fv[j]     * eps1 + g0[j]);
                        av[j + 4] = (__bf16)((float)fv[j + 4] * eps1 + g1[j]);
                    }
                    a[kk] = av;
                }
            }
        } else {
#pragma unroll
            for (int kk = 0; kk < 4; ++kk)
#pragma unroll
                for (int j = 0; j < 8; ++j) a[kk][j] = (__bf16)0.f;
        }
    }

    __syncthreads();  // weights ready; all agg reads above are complete

    const bf16x8* wv = (const bf16x8*)wf;
#pragma unroll
    for (int ct = 0; ct < 8; ++ct) {
        f32x4 acc = {0.f, 0.f, 0.f, 0.f};
#pragma unroll
        for (int kk = 0; kk < 4; ++kk)
            acc = __builtin_amdgcn_mfma_f32_16x16x32_bf16(
                a[kk], wv[(ct * 4 + kk) * 64 + lane], acc, 0, 0, 0);
        float bias = ldf(b1, ct * 16 + r, fB1);
#pragma unroll
        for (int gg = 0; gg < 4; ++gg)   // D: m = quad*4+gg, n = ct*16+r
            h1t[(wave * 16 + quad * 4 + gg) * 136 + ct * 16 + r] =
                (__bf16)lrelu(acc[gg] + bias);
    }
    __syncthreads();  // h1 complete; wf free to reuse

    bf16x8 a2[4];
#pragma unroll
    for (int kk = 0; kk < 4; ++kk)
        a2[kk] = *(const bf16x8*)&h1t[(wave * 16 + r) * 136 + kk * 32 + quad * 8];

    if (PREP) copy_wfrag(pW2, wf, tid);
    else      fill_wfrag(W2, flags[fiW2] != 0, wf, tid);
    __syncthreads();  // W2 frags ready

#pragma unroll
    for (int ct = 0; ct < 8; ++ct) {
        f32x4 acc = {0.f, 0.f, 0.f, 0.f};
#pragma unroll
        for (int kk = 0; kk < 4; ++kk)
            acc = __builtin_amdgcn_mfma_f32_16x16x32_bf16(
                a2[kk], wv[(ct * 4 + kk) * 64 + lane], acc, 0, 0, 0);
        float bias = ldf(b2, ct * 16 + r, fB2);
#pragma unroll
        for (int gg = 0; gg < 4; ++gg) {
            int row = rowBase + quad * 4 + gg;
            if (row < N) {
                int col = ct * 16 + r;
                float v = lrelu(acc[gg] + bias);
                if (RESIDUAL) v += ldf(feat, (size_t)row * DDIM + col, fF);
                out[(size_t)row * DDIM + col] = v;
            }
        }
    }
}

extern "C" void kernel_launch(void* const* d_in, const int* in_sizes, int n_in,
                              void* d_out, int out_size, void* d_ws, size_t ws_size,
                              hipStream_t stream)
{
    const int* src_c2r = (const int*)d_in[2];
    const int* dst_c2r = (const int*)d_in[3];
    const int* src_r2c = (const int*)d_in[5];
    const int* dst_r2c = (const int*)d_in[6];
    const int nE = in_sizes[2];

    // ws layout
    int*    flags  = (int*)d_ws;                                   // 32 ints
    __bf16* wfprep = (__bf16*)((char*)d_ws + 128);                 // 128 KB
    int*    counts = (int*)((char*)d_ws + 128 + 131072);           // 50000
    int*    slots  = counts + NROW;                                // 50000*CAP
    const size_t NEED = 128 + 131072 + (size_t)NROW * 4
                      + (size_t)NROW * CAP * 4;
    const bool big = ws_size >= NEED;

    TensorTab T;
    for (int i = 0; i < 18; ++i) { T.p[i] = d_in[i]; T.n[i] = in_sizes[i]; }

    // OUTPUT IS F32. out_col half doubles as the f32 agg buffer.
    float* out_row = (float*)d_out;
    float* out_col = out_row + (size_t)NROW * DDIM;
    const size_t aggBytes = (size_t)NROW * DDIM * sizeof(float);   // 25.6 MB

    const int eblocks  = (nE + 255) / 256;
    const int sblocks  = (nE * 32 + 255) / 256;
    const int mblocksR = (NROW + 63) / 64;
    const int mblocksC = (NCOL + 63) / 64;
    const int gblocks  = (NROW + 3) / 4;

    detect_dtypes<<<1, 256, 0, stream>>>(T, flags);

    if (big) {
        WPtrs P;
        P.W[0] = d_in[8];  P.fi[0] = 8;    // W1_c2r
        P.W[1] = d_in[10]; P.fi[1] = 10;   // W2_c2r
        P.W[2] = d_in[12]; P.fi[2] = 12;   // W1_r2c
        P.W[3] = d_in[14]; P.fi[3] = 14;   // W2_r2c
        prep_weights<<<32, 256, 0, stream>>>(P, flags, wfprep);

        // ---- stage 1: col -> row ----
        hipMemsetAsync(counts, 0, (size_t)NROW * 4, stream);
        hipMemsetAsync(out_col, 0, aggBytes, stream);
        fill_slots<<<eblocks, 256, 0, stream>>>(dst_c2r, nE, counts, slots,
            d_in[1], src_c2r, d_in[4], out_col, flags, 1, 4);
        segsum<<<gblocks, 256, 0, stream>>>(d_in[1], src_c2r, d_in[4],
            counts, slots, out_col, NROW, flags, 1, 4);
        mlp_kernel<false, true><<<mblocksR, 256, 0, stream>>>(
            d_in[0], out_col, d_in[8], d_in[9], d_in[10], d_in[11], d_in[16],
            out_row, NROW, flags, 0, 8, 9, 10, 11, 16,
            wfprep + 0 * 16384, wfprep + 1 * 16384);

        // ---- stage 2: row -> col ----
        hipMemsetAsync(counts, 0, (size_t)NROW * 4, stream);
        hipMemsetAsync(out_col, 0, aggBytes, stream);
        fill_slots<<<eblocks, 256, 0, stream>>>(dst_r2c, nE, counts, slots,
            out_row, src_r2c, d_in[7], out_col, flags, -1, 7);
        segsum<<<gblocks, 256, 0, stream>>>(out_row, src_r2c, d_in[7],
            counts, slots, out_col, NCOL, flags, -1, 7);
        residual_add<<<(NROW * DDIM / 4 + 255) / 256, 256, 0, stream>>>(
            out_row, d_in[0], NROW * DDIM / 4, flags, 0);
        mlp_kernel<true, true><<<mblocksC, 256, 0, stream>>>(
            d_in[1], out_col, d_in[12], d_in[13], d_in[14], d_in[15], d_in[17],
            out_col, NCOL, flags, 1, 12, 13, 14, 15, 17,
            wfprep + 2 * 16384, wfprep + 3 * 16384);
    } else {
        // legacy round-5 path (atomic scatter, internal weight fill)
        hipMemsetAsync(out_col, 0, aggBytes, stream);
        scatter_any<<<sblocks, 256, 0, stream>>>(d_in[1], src_c2r, dst_c2r,
            d_in[4], out_col, nE, flags, 1, 4);
        mlp_kernel<false, false><<<mblocksR, 256, 0, stream>>>(
            d_in[0], out_col, d_in[8], d_in[9], d_in[10], d_in[11], d_in[16],
            out_row, NROW, flags, 0, 8, 9, 10, 11, 16, nullptr, nullptr);

        hipMemsetAsync(out_col, 0, aggBytes, stream);
        scatter_any<<<sblocks, 256, 0, stream>>>(out_row, src_r2c, dst_r2c,
            d_in[7], out_col, nE, flags, -1, 7);
        residual_add<<<(NROW * DDIM / 4 + 255) / 256, 256, 0, stream>>>(
            out_row, d_in[0], NROW * DDIM / 4, flags, 0);
        mlp_kernel<true, false><<<mblocksC, 256, 0, stream>>>(
            d_in[1], out_col, d_in[12], d_in[13], d_in[14], d_in[15], d_in[17],
            out_col, NCOL, flags, 1, 12, 13, 14, 15, 17, nullptr, nullptr);
    }
}